// Round 2
// baseline (94.529 us; speedup 1.0000x reference)
//
#include <hip/hip_runtime.h>

#define B_N    1024
#define DIM_I  256
#define DIM_J  256
#define NUM_K  64
#define CHUNKS 4
#define I_PER  (DIM_I / CHUNKS)   // 64

__device__ __forceinline__ unsigned bf16bits(float f) {
    // round-to-nearest-even bf16 (inputs are small finite values, no NaN/Inf)
    unsigned b = __float_as_uint(f);
    return (b + 0x7FFFu + ((b >> 16) & 1u)) >> 16;
}

// ---------------------------------------------------------------------------
// Kernel 1: transpose + downconvert + k-pair pack
//   Y [I][J][K] f32  ->  Y3 [I][K][J] u32, where dword = bf16(Y[i,j,k])
//                                            | bf16(Y[i,j,k+1]) << 16
// So the (k0, k0+1) lerp gather in the main kernel is ONE dword per (i,j).
// One block per (i, 64-wide j-tile); reads and writes fully coalesced.
// ---------------------------------------------------------------------------
__global__ __launch_bounds__(256) void kan_pack(const float* __restrict__ Y,
                                                unsigned* __restrict__ Y3) {
    __shared__ float lds[64][65];  // +1 pad: conflict-free column reads
    const int i  = blockIdx.x >> 2;
    const int j0 = (blockIdx.x & 3) << 6;
    const float* src = Y + (size_t)(i * DIM_J + j0) * NUM_K;

    for (int e = threadIdx.x; e < 4096; e += 256)
        lds[e >> 6][e & 63] = src[e];   // 16 KB contiguous span
    __syncthreads();
    for (int e = threadIdx.x; e < 4096; e += 256) {
        int kl = e >> 6, jl = e & 63;   // consecutive lanes -> consecutive j
        float v0 = lds[jl][kl];
        float v1 = (kl < 63) ? lds[jl][kl + 1] : 0.0f;  // k=63 row never read
        Y3[(i * NUM_K + kl) * DIM_J + j0 + jl] = bf16bits(v0) | (bf16bits(v1) << 16);
    }
}

// ---------------------------------------------------------------------------
// Kernel 2: gather-lerp-reduce over a 64-wide i-chunk
//   part[c,b,j] = sum_{i in chunk c} (1-t)*Y3lo[i,k0,j] + t*Y3hi[i,k0,j]
// 4096 blocks (4 chunks x 1024 b) x 128 threads = 32 waves/CU.
// Each thread owns j-pair -> one dwordx2 gather per i.
// ---------------------------------------------------------------------------
__global__ __launch_bounds__(128) void kan_main(const float* __restrict__ x,
                                                const float* __restrict__ Xg,
                                                const unsigned* __restrict__ Y3,
                                                float* __restrict__ part) {
    __shared__ float  Xs[NUM_K];
    __shared__ float2 ot[I_PER];   // .x = t, .y = int-bits element offset

    const int b = blockIdx.x >> 2;
    const int c = blockIdx.x & 3;
    const int t = threadIdx.x;

    if (t < NUM_K) Xs[t] = Xg[t];
    __syncthreads();

    if (t < I_PER) {
        const int i = c * I_PER + t;
        float xv = x[b * DIM_I + i];
        // uniform grid [-2,2]: closed-form searchsorted(right) + exact fixup
        int m = (int)floorf((xv + 2.0f) * (63.0f / 4.0f)) + 1;
        m = m < 1 ? 1 : (m > 63 ? 63 : m);
        while (m < 63 && Xs[m] <= xv) ++m;
        while (m > 1 && Xs[m - 1] > xv) --m;
        float x0 = Xs[m - 1], x1 = Xs[m];
        float tt = (xv - x0) / (x1 - x0);
        int off = (i * NUM_K + (m - 1)) * DIM_J;   // dword row k0 of Y3[i]
        ot[t] = make_float2(tt, __int_as_float(off));
    }
    __syncthreads();

    const int jp = t << 1;
    float acc0 = 0.f, acc1 = 0.f;
    #pragma unroll 8
    for (int i = 0; i < I_PER; ++i) {
        float2 o  = ot[i];                 // wave-uniform ds_read_b64
        float  tt = o.x;
        float  s  = 1.0f - tt;
        int    off = __float_as_int(o.y);
        uint2  p  = *reinterpret_cast<const uint2*>(Y3 + off + jp);  // 8B/lane
        float a0 = __uint_as_float(p.x << 16);          // Y[i,jp,  k0]
        float b0 = __uint_as_float(p.x & 0xFFFF0000u);  // Y[i,jp,  k0+1]
        float a1 = __uint_as_float(p.y << 16);          // Y[i,jp+1,k0]
        float b1 = __uint_as_float(p.y & 0xFFFF0000u);  // Y[i,jp+1,k0+1]
        acc0 = fmaf(s, a0, acc0); acc0 = fmaf(tt, b0, acc0);
        acc1 = fmaf(s, a1, acc1); acc1 = fmaf(tt, b1, acc1);
    }
    *reinterpret_cast<float2*>(part + ((c << 10) + b) * DIM_J + jp)
        = make_float2(acc0, acc1);
}

// ---------------------------------------------------------------------------
// Kernel 3: sum the 4 chunk partials. [c][b][j] layout -> 4 coalesced streams.
// ---------------------------------------------------------------------------
__global__ __launch_bounds__(256) void kan_reduce(const float* __restrict__ part,
                                                  float* __restrict__ out) {
    const int idx = blockIdx.x * 256 + threadIdx.x;
    const int BJ = B_N * DIM_J;
    out[idx] = (part[idx] + part[BJ + idx]) + (part[2 * BJ + idx] + part[3 * BJ + idx]);
}

extern "C" void kernel_launch(void* const* d_in, const int* in_sizes, int n_in,
                              void* d_out, int out_size, void* d_ws, size_t ws_size,
                              hipStream_t stream) {
    const float* x  = (const float*)d_in[0];
    const float* Xg = (const float*)d_in[1];
    const float* Y  = (const float*)d_in[2];
    float* out = (float*)d_out;

    unsigned* Y3  = (unsigned*)d_ws;                       // 16.8 MB
    float*    prt = (float*)((char*)d_ws + (32u << 20));   // 4 MB @ +32MB

    kan_pack  <<<B_N,            256, 0, stream>>>(Y, Y3);
    kan_main  <<<B_N * CHUNKS,   128, 0, stream>>>(x, Xg, Y3, prt);
    kan_reduce<<<B_N,            256, 0, stream>>>(prt, out);
}